// Round 4
// baseline (553.848 us; speedup 1.0000x reference)
//
#include <hip/hip_runtime.h>

#define M_TOK 8192
#define N_OUT 4096
#define K_IN  4096
#define NT    (K_IN / 64)                    // 64 K-tiles of BK=64
#define CVT_BLOCKS ((M_TOK * K_IN) / 2048)   // 16384: 256 thr * 8 f32 each
#define DEQ_BLOCKS (N_OUT * 4 / 4)           // 4096: 4 waves/block, 1 group/wave

typedef __bf16 bf16x8 __attribute__((ext_vector_type(8)));
typedef float f32x4 __attribute__((ext_vector_type(4)));

__device__ __forceinline__ unsigned short f2b(float f) {
  union { float f; unsigned u; } c; c.f = f;
  unsigned u = c.u;
  return (unsigned short)((u + 0x7FFFu + ((u >> 16) & 1u)) >> 16);  // RNE
}

// ---------------- kernel 1: fused x-cast + W dequant/FWHT (unchanged) ----------------
__global__ __launch_bounds__(256) void prep_kernel(const float* __restrict__ x,
                                                   unsigned short* __restrict__ xb,
                                                   const int* __restrict__ codes,
                                                   const float* __restrict__ grid,
                                                   const float* __restrict__ scales,
                                                   unsigned short* __restrict__ Wt) {
  if (blockIdx.x < CVT_BLOCKS) {
    long i = ((long)blockIdx.x * 256 + threadIdx.x) * 8;
    float4 a = *(const float4*)(x + i);
    float4 b = *(const float4*)(x + i + 4);
    union { unsigned short us[8]; uint4 v; } o;
    o.us[0] = f2b(a.x); o.us[1] = f2b(a.y); o.us[2] = f2b(a.z); o.us[3] = f2b(a.w);
    o.us[4] = f2b(b.x); o.us[5] = f2b(b.y); o.us[6] = f2b(b.z); o.us[7] = f2b(b.w);
    *(uint4*)(xb + i) = o.v;
  } else {
    int bid = blockIdx.x - CVT_BLOCKS;
    int wave = threadIdx.x >> 6;
    int lane = threadIdx.x & 63;
    int G = bid * 4 + wave;
    int o = G >> 2;
    int g = G & 3;
    const int* crow = codes + (long)o * 2048 + g * 512 + lane * 8;
    int4 c0 = *(const int4*)crow;
    int4 c1 = *(const int4*)(crow + 4);
    float v[16];
    const float2* g2p = (const float2*)grid;
    float2 t;
    t = g2p[c0.x]; v[0] = t.x;  v[1] = t.y;
    t = g2p[c0.y]; v[2] = t.x;  v[3] = t.y;
    t = g2p[c0.z]; v[4] = t.x;  v[5] = t.y;
    t = g2p[c0.w]; v[6] = t.x;  v[7] = t.y;
    t = g2p[c1.x]; v[8] = t.x;  v[9] = t.y;
    t = g2p[c1.y]; v[10] = t.x; v[11] = t.y;
    t = g2p[c1.z]; v[12] = t.x; v[13] = t.y;
    t = g2p[c1.w]; v[14] = t.x; v[15] = t.y;
#pragma unroll
    for (int s = 1; s < 16; s <<= 1) {
#pragma unroll
      for (int base = 0; base < 16; base++) {
        if (!(base & s)) {
          float a = v[base], b = v[base | s];
          v[base] = a + b;
          v[base | s] = a - b;
        }
      }
    }
#pragma unroll
    for (int m = 1; m <= 32; m <<= 1) {
      bool hi = (lane & m) != 0;
#pragma unroll
      for (int c = 0; c < 16; c++) {
        float p = __shfl_xor(v[c], m, 64);
        v[c] = hi ? p - v[c] : p + v[c];
      }
    }
    float sc = scales[o * 4 + g] * 0.03125f;
    union { unsigned short us[16]; uint4 q[2]; } out;
#pragma unroll
    for (int c = 0; c < 16; c++) out.us[c] = f2b(v[c] * sc);
    unsigned short* wp = Wt + (long)o * 4096 + g * 1024 + lane * 16;
    *(uint4*)wp = out.q[0];
    *(uint4*)(wp + 8) = out.q[1];
  }
}

// ---------------- kernel 2: 256x256-tile deep-pipelined bf16 GEMM, C = A*B^T + bias ----
// 8 waves (2M x 4N), per-wave 128x64 out. BK=64, LDS = 2 x (A 32KB + B 32KB) = 128 KiB.
// Granule XOR swizzle (T2): granule g holds global chunk ((g&7)^((g>>3)&7)) of row g>>3.
// Phase order chosen for PROGRESSIVE SLOT RETIREMENT:
//   P0: mi0-3 kk0 (reads B-kk0, A-lo-kk0)   P1: mi0-3 kk1 (reads B-kk1, A-lo-kk1)
//   P2: mi4-7 kk0 (reads A-hi-kk0; B regs)  P3: mi4-7 kk1 (reads A-hi-kk1; B regs)
// -> B slots + A-lo (a0,a2) slots retire at P1-mid barrier; A-hi (a1,a3) at P3-mid.
// Tile T+2's loads are issued into buffer p_T right after the retiring barrier:
//   P1-post: b0b1(T+2) | P2-post: b2b3(T+2), a0a2(T+2) | P3-post: a1a3(T+2).
// Two counted waits per tile, both vmcnt(10), each with 5-7 phases of slack:
//   W_B at P1-end guards a1a3(T) (needed P2);  W_A at P3-end guards b*,a0a2(T+1).
// Up to 16 loads in flight; never drains in the main loop (T4). setprio on MFMA (T5).
__device__ __forceinline__ void load16_to_lds(const unsigned short* g, unsigned short* l) {
  __builtin_amdgcn_global_load_lds((const __attribute__((address_space(1))) void*)g,
                                   (__attribute__((address_space(3))) void*)l,
                                   16, 0, 0);
}

__device__ __forceinline__ void phase_barrier() {
  __builtin_amdgcn_s_barrier();
  __builtin_amdgcn_sched_barrier(0);
}

__global__ __launch_bounds__(512, 2) void gemm_kernel(const unsigned short* __restrict__ A,
                                                      const unsigned short* __restrict__ B,
                                                      const float* __restrict__ bias,
                                                      float* __restrict__ C) {
  __shared__ unsigned short sA[2][256 * 64];
  __shared__ unsigned short sB[2][256 * 64];

  // XCD-chunked bijective swizzle: 512 wgs, 8 XCDs -> each XCD a contiguous 64-wg chunk.
  const int wg  = blockIdx.x;
  const int swz = (wg & 7) * (512 / 8) + (wg >> 3);
  const int bn  = (swz & 15) * 256;   // 16 N-tiles
  const int bm  = (swz >> 4) * 256;   // 32 M-tiles

  const int tid  = threadIdx.x;
  const int wave = tid >> 6;
  const int lane = tid & 63;
  const int wm   = wave >> 2;         // 0..1  (M half)
  const int wn   = wave & 3;          // 0..3  (N quarter)

  // ---- staging: thread covers granule tid + j*512 (group j = rows j*64..j*64+63) ----
  const long K = K_IN;
  const unsigned short* aSrc[4];
  const unsigned short* bSrc[4];
  unsigned short* aDst[4];
  unsigned short* bDst[4];
#pragma unroll
  for (int j = 0; j < 4; j++) {
    const int g   = tid + j * 512;
    const int row = g >> 3;
    const int cg  = (g & 7) ^ (row & 7);          // inverse-swizzled global chunk
    aSrc[j] = A + (long)(bm + row) * K + cg * 8;
    bSrc[j] = B + (long)(bn + row) * K + cg * 8;
    aDst[j] = &sA[0][g * 8];
    bDst[j] = &sB[0][g * 8];
  }

  // ---- fragment read offsets (ushort elements), granule-XOR applied ----
  const int m7  = lane & 7;
  const int cb  = lane >> 4;                       // k-chunk base 0..3
  const int r0a = wm * 128 + (lane & 15);
  const int r0b = wn * 64  + (lane & 15);
  const int aoff0 = (r0a * 8 + ( cb      ^ m7)) * 8;   // kk=0
  const int aoff1 = (r0a * 8 + ((cb | 4) ^ m7)) * 8;   // kk=1
  const int boff0 = (r0b * 8 + ( cb      ^ m7)) * 8;
  const int boff1 = (r0b * 8 + ((cb | 4) ^ m7)) * 8;

  f32x4 acc[8][4] = {};

  // ---- prologue: stage tiles 0 and 1 in stream order [b01, b23, a02, a13] each ----
  load16_to_lds(bSrc[0], bDst[0]);
  load16_to_lds(bSrc[1], bDst[1]);
  load16_to_lds(bSrc[2], bDst[2]);
  load16_to_lds(bSrc[3], bDst[3]);
  load16_to_lds(aSrc[0], aDst[0]);
  load16_to_lds(aSrc[2], aDst[2]);
  load16_to_lds(aSrc[1], aDst[1]);
  load16_to_lds(aSrc[3], aDst[3]);
  load16_to_lds(bSrc[0] + 64, bDst[0] + 16384);
  load16_to_lds(bSrc[1] + 64, bDst[1] + 16384);
  load16_to_lds(bSrc[2] + 64, bDst[2] + 16384);
  load16_to_lds(bSrc[3] + 64, bDst[3] + 16384);
  load16_to_lds(aSrc[0] + 64, aDst[0] + 16384);
  load16_to_lds(aSrc[2] + 64, aDst[2] + 16384);
  load16_to_lds(aSrc[1] + 64, aDst[1] + 16384);
  load16_to_lds(aSrc[3] + 64, aDst[3] + 16384);
  asm volatile("s_waitcnt vmcnt(10)" ::: "memory");   // tile0's b*, a0, a2 landed
  phase_barrier();

  for (int t = 0; t < NT; t++) {
    const int p = t & 1;
    const unsigned short* bufA = &sA[p][0];
    const unsigned short* bufB = &sB[p][0];
    const bool pf   = (t + 2 < NT);
    const int  koff = (t + 2) * 64;
    const int  q16  = p * 16384;          // tile t+2 has same buffer parity as t

    bf16x8 av[4], bk0[4], bk1[4];

    // ---- P0: mi0-3 kk0 ----
#pragma unroll
    for (int i = 0; i < 4; i++) bk0[i] = *(const bf16x8*)(bufB + boff0 + i * 1024);
#pragma unroll
    for (int i = 0; i < 4; i++) av[i]  = *(const bf16x8*)(bufA + aoff0 + i * 1024);
    phase_barrier();   // P0-mid
    __builtin_amdgcn_s_setprio(1);
#pragma unroll
    for (int mi = 0; mi < 4; mi++)
#pragma unroll
      for (int ni = 0; ni < 4; ni++)
        acc[mi][ni] = __builtin_amdgcn_mfma_f32_16x16x32_bf16(av[mi], bk0[ni], acc[mi][ni], 0, 0, 0);
    __builtin_amdgcn_s_setprio(0);
    phase_barrier();   // P0-end

    // ---- P1: mi0-3 kk1 | issue b0b1(t+2) after B/A-lo slots retire at P1-mid ----
#pragma unroll
    for (int i = 0; i < 4; i++) bk1[i] = *(const bf16x8*)(bufB + boff1 + i * 1024);
#pragma unroll
    for (int i = 0; i < 4; i++) av[i]  = *(const bf16x8*)(bufA + aoff1 + i * 1024);
    phase_barrier();   // P1-mid (retires B + a0/a2 slots of buffer p)
    if (pf) {
      load16_to_lds(bSrc[0] + koff, bDst[0] + q16);
      load16_to_lds(bSrc[1] + koff, bDst[1] + q16);
    }
    __builtin_amdgcn_s_setprio(1);
#pragma unroll
    for (int mi = 0; mi < 4; mi++)
#pragma unroll
      for (int ni = 0; ni < 4; ni++)
        acc[mi][ni] = __builtin_amdgcn_mfma_f32_16x16x32_bf16(av[mi], bk1[ni], acc[mi][ni], 0, 0, 0);
    __builtin_amdgcn_s_setprio(0);
    // W_B: guard this tile's a1,a3 (read at P2). 5+ phases of slack.
    if (t < NT - 2)      asm volatile("s_waitcnt vmcnt(10)" ::: "memory");
    else if (t == NT - 2) asm volatile("s_waitcnt vmcnt(8)" ::: "memory");
    else                 asm volatile("s_waitcnt vmcnt(0)" ::: "memory");
    phase_barrier();   // P1-end (publishes a1,a3 of tile t)

    // ---- P2: mi4-7 kk0 (B from bk0 regs) | issue b2b3(t+2), a0a2(t+2) ----
#pragma unroll
    for (int i = 0; i < 4; i++) av[i] = *(const bf16x8*)(bufA + aoff0 + 4096 + i * 1024);
    phase_barrier();   // P2-mid
    if (pf) {
      load16_to_lds(bSrc[2] + koff, bDst[2] + q16);
      load16_to_lds(bSrc[3] + koff, bDst[3] + q16);
      load16_to_lds(aSrc[0] + koff, aDst[0] + q16);
      load16_to_lds(aSrc[2] + koff, aDst[2] + q16);
    }
    __builtin_amdgcn_s_setprio(1);
#pragma unroll
    for (int mi = 0; mi < 4; mi++)
#pragma unroll
      for (int ni = 0; ni < 4; ni++)
        acc[4 + mi][ni] = __builtin_amdgcn_mfma_f32_16x16x32_bf16(av[mi], bk0[ni], acc[4 + mi][ni], 0, 0, 0);
    __builtin_amdgcn_s_setprio(0);
    phase_barrier();   // P2-end

    // ---- P3: mi4-7 kk1 (B from bk1 regs) | issue a1a3(t+2) after P3-mid retires them ----
#pragma unroll
    for (int i = 0; i < 4; i++) av[i] = *(const bf16x8*)(bufA + aoff1 + 4096 + i * 1024);
    phase_barrier();   // P3-mid (retires a1/a3 slots of buffer p)
    if (pf) {
      load16_to_lds(aSrc[1] + koff, aDst[1] + q16);
      load16_to_lds(aSrc[3] + koff, aDst[3] + q16);
    }
    __builtin_amdgcn_s_setprio(1);
#pragma unroll
    for (int mi = 0; mi < 4; mi++)
#pragma unroll
      for (int ni = 0; ni < 4; ni++)
        acc[4 + mi][ni] = __builtin_amdgcn_mfma_f32_16x16x32_bf16(av[mi], bk1[ni], acc[4 + mi][ni], 0, 0, 0);
    __builtin_amdgcn_s_setprio(0);
    // W_A: guard next tile's b*, a0, a2 (read at its P0). 5+ phases of slack.
    if (t < NT - 2)      asm volatile("s_waitcnt vmcnt(10)" ::: "memory");
    else if (t == NT - 2) asm volatile("s_waitcnt vmcnt(2)" ::: "memory");
    phase_barrier();   // P3-end (publishes next tile's P0 data)
  }

  // ---- epilogue: D[m=(lane>>4)*4+r][n=lane&15] per 16x16 tile ----
  const int cn  = lane & 15;
  const int cm4 = (lane >> 4) * 4;
#pragma unroll
  for (int ni = 0; ni < 4; ni++) {
    const int col = bn + wn * 64 + ni * 16 + cn;
    const float bb = bias[col];
#pragma unroll
    for (int mi = 0; mi < 8; mi++) {
#pragma unroll
      for (int r = 0; r < 4; r++) {
        const int row = bm + wm * 128 + mi * 16 + cm4 + r;
        C[(long)row * N_OUT + col] = acc[mi][ni][r] + bb;
      }
    }
  }
}

extern "C" void kernel_launch(void* const* d_in, const int* in_sizes, int n_in,
                              void* d_out, int out_size, void* d_ws, size_t ws_size,
                              hipStream_t stream) {
  const float* x      = (const float*)d_in[0];
  const int*   codes  = (const int*)d_in[1];
  const float* grid   = (const float*)d_in[2];
  const float* scales = (const float*)d_in[3];
  const float* bias   = (const float*)d_in[4];
  float* out = (float*)d_out;

  unsigned short* xb = (unsigned short*)d_ws;                    // 64 MiB bf16
  unsigned short* Wt = xb + (size_t)M_TOK * K_IN;                // 32 MiB bf16

  prep_kernel<<<CVT_BLOCKS + DEQ_BLOCKS, 256, 0, stream>>>(x, xb, codes, grid, scales, Wt);
  gemm_kernel<<<512, 512, 0, stream>>>(xb, Wt, bias, out);
}